// Round 4
// baseline (292.796 us; speedup 1.0000x reference)
//
#include <hip/hip_runtime.h>
#include <math.h>

#define N_OBS   2048
#define DIM_IN  64
#define K_HID   1024
#define NCHUNK  (N_OBS / 64)                // 32 n-chunks of 64

typedef unsigned short ushort_t;
typedef __attribute__((ext_vector_type(8))) short bf16x8;
typedef __attribute__((ext_vector_type(4))) float f32x4;

__device__ __forceinline__ ushort_t f2bf(float f) {
    unsigned int u = __float_as_uint(f);
    u += 0x7FFF + ((u >> 16) & 1);          // round-to-nearest-even
    return (ushort_t)(u >> 16);
}

// async global->LDS, 16B per lane, LDS dest = wave-uniform base + lane*16
#define GLD_LDS16(g, l)                                                   \
    __builtin_amdgcn_global_load_lds(                                     \
        (const __attribute__((address_space(1))) void*)(g),               \
        (__attribute__((address_space(3))) void*)(l), 16, 0, 0)

// ---------------------------------------------------------------------------
// Kernel 1: sT[k,n] = bf16( -sqrt(2/K) * sin( dot(x[n,:], w[k,:]) + b[k] ) )
// Block tile: 16 n x 64 k. wT LDS pad=65 -> conflict-free per-lane reads.
// ---------------------------------------------------------------------------
__global__ __launch_bounds__(256) void rff_compute_s(
    const float* __restrict__ x, const float* __restrict__ w,
    const float* __restrict__ b, ushort_t* __restrict__ sT) {
    __shared__ float xs[16][64];
    __shared__ float wT[64][65];             // [d][k], pad 65: bank = (d+k)%32

    const int t  = threadIdx.x;
    const int k0 = blockIdx.x * 64;
    const int n0 = blockIdx.y * 16;

    {   // x tile: 256 float4
        int r = t >> 4, c = (t & 15) * 4;
        *(float4*)&xs[r][c] = *(const float4*)(x + (n0 + r) * DIM_IN + c);
    }
#pragma unroll
    for (int i = 0; i < 4; ++i) {            // w tile, transposed into LDS
        int r = (t >> 4) + 16 * i, c = (t & 15) * 4;
        float4 v = *(const float4*)(w + (k0 + r) * DIM_IN + c);
        wT[c + 0][r] = v.x; wT[c + 1][r] = v.y;
        wT[c + 2][r] = v.z; wT[c + 3][r] = v.w;
    }
    __syncthreads();

    const int k  = t & 63;                   // lane = k -> conflict-free wT reads
    const int nb = t >> 6;                   // wave-uniform -> xs reads broadcast
    const float bk = b[k0 + k];
    float z[4];
#pragma unroll
    for (int i = 0; i < 4; ++i) z[i] = bk;

    for (int d4 = 0; d4 < 64; d4 += 4) {
        float xv[4][4];
#pragma unroll
        for (int i = 0; i < 4; ++i)
            *(float4*)xv[i] = *(const float4*)&xs[nb * 4 + i][d4];
#pragma unroll
        for (int j = 0; j < 4; ++j) {
            const float wv = wT[d4 + j][k];
#pragma unroll
            for (int i = 0; i < 4; ++i) z[i] += xv[i][j] * wv;
        }
    }

    const float scale = 0.04419417382415922f;  // sqrt(2/1024)
    ushort4 ov;
    ov.x = f2bf(-scale * __sinf(z[0]));
    ov.y = f2bf(-scale * __sinf(z[1]));
    ov.z = f2bf(-scale * __sinf(z[2]));
    ov.w = f2bf(-scale * __sinf(z[3]));
    *(ushort4*)(sT + (size_t)(k0 + k) * N_OBS + n0 + nb * 4) = ov;
}

// ---------------------------------------------------------------------------
// Kernel 2 (FUSED gram + scale + expand), 512 threads = 8 waves:
// Per block (grid 16x16, 1 block/CU, 2 waves/SIMD): compute the 64x64 M-tile
//   M[k,l] = (1/n) sum_n s[n,k] s[n,l]
// via the 3-buffer depth-2 global_load_lds pipeline with COUNTED vmcnt:
// per iteration: vmcnt(2) [drains own stage(it), leaves stage(it+1) in
// flight] -> s_barrier -> issue stage(it+2) [its buffer's readers (it-1)
// are past the barrier] -> ds_read + MFMA on buf[it%3].
// 8 waves: wave wv computes quadrant rows (wv>>2)*32..+32, cols (wv&3)*16..+16
// (acc[2] of f32x4 only), and stages A-chunk wv + B-chunk wv (2 loads/wave).
// Then write all 64 d-planes:
//   out[d, k0+row, l0+col] = M[row,col] * w[k0+row,d] * w[l0+col,d]
// with full-line nontemporal f32x4 stores (268 MB = the HBM write floor).
// LDS phases alias one 51 KB arena: phase-1 staging (3 x 16 KB) is dead
// before phase-2 writes M_lds/wkT/wlT (stride 68 floats).
// ---------------------------------------------------------------------------
__device__ __forceinline__ void stage_tiles(
    const ushort_t* __restrict__ sT, ushort_t* buf,
    int k0, int l0, int ncol0, int wv, int srow, int sslot) {
    const ushort_t* gA = sT + (size_t)(k0 + wv * 8 + srow) * N_OBS + ncol0 + sslot * 8;
    const ushort_t* gB = sT + (size_t)(l0 + wv * 8 + srow) * N_OBS + ncol0 + sslot * 8;
    GLD_LDS16(gA, buf + wv * 512);           // A: chunk wv -> [wv*1024B, +1024)
    GLD_LDS16(gB, buf + 4096 + wv * 512);    // B: second 8 KB half
}

__global__ __launch_bounds__(512, 2) void rff_gram_expand(
    const ushort_t* __restrict__ sT, const float* __restrict__ w,
    float* __restrict__ out) {
    __shared__ __align__(16) char smem[52224];
    ushort_t* stg   = (ushort_t*)smem;              // phase1: 3 bufs x 8192 bf16
    float*    M_lds = (float*)smem;                 // phase2+: [64][68]
    float*    wkT   = (float*)(smem + 17408);       // phase2+: [64][68] (d-major)
    float*    wlT   = (float*)(smem + 34816);       // phase2+: [64][68]

    const int t    = threadIdx.x;
    const int lane = t & 63;
    const int wv   = t >> 6;                 // 0..7
    const int wr   = wv >> 2, wc = wv & 3;   // quadrant: rows wr*32, cols wc*16
    const int k0   = blockIdx.y * 64, l0 = blockIdx.x * 64;

    // Staging geometry: lds[row][slot] holds global col-slot (slot ^ (row&7)).
    const int srow  = lane >> 3;
    const int sslot = (lane & 7) ^ srow;

    f32x4 acc[2];
#pragma unroll
    for (int a = 0; a < 2; ++a)
        acc[a] = (f32x4){0.f, 0.f, 0.f, 0.f};

    const int rlo = lane & 15;               // fragment row within 16
    const int hi  = lane >> 4;               // 0..3 -> k sub-slot
    const int rx  = rlo & 7;                 // row&7 for the read-side XOR

    // prologue: fill pipeline 2 deep (2 loads/wave each)
    stage_tiles(sT, stg,        k0, l0,  0, wv, srow, sslot);
    stage_tiles(sT, stg + 8192, k0, l0, 64, wv, srow, sslot);

    for (int it = 0; it < NCHUNK; ++it) {
        if (it == NCHUNK - 1) {              // tail: drain everything
            asm volatile("s_waitcnt vmcnt(0)" ::: "memory");
        } else {                             // steady: drain own stage(it) only
            asm volatile("s_waitcnt vmcnt(2)" ::: "memory");
        }
        __builtin_amdgcn_s_barrier();        // all waves' stage(it) landed
        if (it + 2 < NCHUNK)                 // issue stage(it+2); its buffer's
            stage_tiles(sT, stg + ((it + 2) % 3) * 8192,   // readers (it-1) are
                        k0, l0, (it + 2) * 64, wv, srow, sslot);  // past barrier
        const ushort_t* bufA = stg + (it % 3) * 8192;
        const ushort_t* bufB = bufA + 4096;
#pragma unroll
        for (int ks = 0; ks < 2; ++ks) {     // two K=32 steps per 64-chunk
            const int slot = (ks * 4 + hi) ^ rx;   // swizzled read slot
            bf16x8 af[2], bfr;
#pragma unroll
            for (int a = 0; a < 2; ++a)
                af[a] = *(const bf16x8*)(bufA + (wr * 32 + a * 16 + rlo) * 64 + slot * 8);
            bfr = *(const bf16x8*)(bufB + (wc * 16 + rlo) * 64 + slot * 8);
#pragma unroll
            for (int a = 0; a < 2; ++a)
                acc[a] = __builtin_amdgcn_mfma_f32_16x16x32_bf16(
                    af[a], bfr, acc[a], 0, 0, 0);
        }
    }
    __syncthreads();                         // all staging reads retired; LDS
                                             // arena may now be re-purposed

    // ---- phase 2: acc -> M_lds (scaled); w tiles -> LDS transposed ----
    const float inv_n = 1.0f / (float)N_OBS;
    const int col = lane & 15;
    const int rq  = (lane >> 4) * 4;
#pragma unroll
    for (int a = 0; a < 2; ++a)
#pragma unroll
        for (int r = 0; r < 4; ++r) {
            const int row = wr * 32 + a * 16 + rq + r;
            const int cl  = wc * 16 + col;
            M_lds[row * 68 + cl] = acc[a][r] * inv_n;
        }
#pragma unroll
    for (int i = 0; i < 2; ++i) {            // wkT[d][kk]=w[k0+kk][d], wlT likewise
        const int r = (t >> 4) + 32 * i, c = (t & 15) * 4;
        float4 vk = *(const float4*)(w + (k0 + r) * DIM_IN + c);
        float4 vl = *(const float4*)(w + (l0 + r) * DIM_IN + c);
        wkT[(c + 0) * 68 + r] = vk.x; wkT[(c + 1) * 68 + r] = vk.y;
        wkT[(c + 2) * 68 + r] = vk.z; wkT[(c + 3) * 68 + r] = vk.w;
        wlT[(c + 0) * 68 + r] = vl.x; wlT[(c + 1) * 68 + r] = vl.y;
        wlT[(c + 2) * 68 + r] = vl.z; wlT[(c + 3) * 68 + r] = vl.w;
    }
    __syncthreads();

    // ---- phase 3: d-sweep, 1 MB of nontemporal full-line stores ----
    const int trow = t >> 4;                 // 0..31
    const int tcol = (t & 15) * 4;           // 0..60
    f32x4 mv[2];                             // M rows hoisted to registers
    mv[0] = *(const f32x4*)&M_lds[trow * 68 + tcol];
    mv[1] = *(const f32x4*)&M_lds[(trow + 32) * 68 + tcol];

    float* outb = out + (size_t)k0 * K_HID + l0;
#pragma unroll 2
    for (int d = 0; d < DIM_IN; ++d) {
        const f32x4 wlv = *(const f32x4*)&wlT[d * 68 + tcol];
        float* outd = outb + (size_t)d * K_HID * K_HID;
        const float wk0 = wkT[d * 68 + trow];
        const float wk1 = wkT[d * 68 + trow + 32];
        f32x4 o0, o1;
#pragma unroll
        for (int j = 0; j < 4; ++j) {
            o0[j] = mv[0][j] * wk0 * wlv[j];
            o1[j] = mv[1][j] * wk1 * wlv[j];
        }
        __builtin_nontemporal_store(
            o0, (f32x4*)(outd + (size_t)trow * K_HID + tcol));
        __builtin_nontemporal_store(
            o1, (f32x4*)(outd + (size_t)(trow + 32) * K_HID + tcol));
    }
}

// ---------------------------------------------------------------------------
extern "C" void kernel_launch(void* const* d_in, const int* in_sizes, int n_in,
                              void* d_out, int out_size, void* d_ws, size_t ws_size,
                              hipStream_t stream) {
    const float* x = (const float*)d_in[0];  // (2048, 64)
    const float* w = (const float*)d_in[1];  // (1024, 64)
    const float* b = (const float*)d_in[2];  // (1024,)
    float* out = (float*)d_out;              // (64, 1024, 1024)

    ushort_t* sT_buf = (ushort_t*)d_ws;      // 4 MB bf16 (1024 x 2048)

    rff_compute_s<<<dim3(K_HID / 64, N_OBS / 16), 256, 0, stream>>>(x, w, b, sT_buf);
    rff_gram_expand<<<dim3(K_HID / 64, K_HID / 64), 512, 0, stream>>>(sT_buf, w, out);
}

// Round 5
// 284.683 us; speedup vs baseline: 1.0285x; 1.0285x over previous
//
#include <hip/hip_runtime.h>
#include <math.h>

#define N_OBS   2048
#define DIM_IN  64
#define K_HID   1024
#define NCHUNK  (N_OBS / 64)                // 32 n-chunks of 64

typedef unsigned short ushort_t;
typedef __attribute__((ext_vector_type(8))) short bf16x8;
typedef __attribute__((ext_vector_type(4))) float f32x4;

__device__ __forceinline__ ushort_t f2bf(float f) {
    unsigned int u = __float_as_uint(f);
    u += 0x7FFF + ((u >> 16) & 1);          // round-to-nearest-even
    return (ushort_t)(u >> 16);
}

// async global->LDS, 16B per lane, LDS dest = wave-uniform base + lane*16
#define GLD_LDS16(g, l)                                                   \
    __builtin_amdgcn_global_load_lds(                                     \
        (const __attribute__((address_space(1))) void*)(g),               \
        (__attribute__((address_space(3))) void*)(l), 16, 0, 0)

// ---------------------------------------------------------------------------
// Kernel 1: sT[k,n] = bf16( -sqrt(2/K) * sin( dot(x[n,:], w[k,:]) + b[k] ) )
// Block tile: 16 n x 64 k. wT LDS pad=65 -> conflict-free per-lane reads.
// ---------------------------------------------------------------------------
__global__ __launch_bounds__(256) void rff_compute_s(
    const float* __restrict__ x, const float* __restrict__ w,
    const float* __restrict__ b, ushort_t* __restrict__ sT) {
    __shared__ float xs[16][64];
    __shared__ float wT[64][65];             // [d][k], pad 65: bank = (d+k)%32

    const int t  = threadIdx.x;
    const int k0 = blockIdx.x * 64;
    const int n0 = blockIdx.y * 16;

    {   // x tile: 256 float4
        int r = t >> 4, c = (t & 15) * 4;
        *(float4*)&xs[r][c] = *(const float4*)(x + (n0 + r) * DIM_IN + c);
    }
#pragma unroll
    for (int i = 0; i < 4; ++i) {            // w tile, transposed into LDS
        int r = (t >> 4) + 16 * i, c = (t & 15) * 4;
        float4 v = *(const float4*)(w + (k0 + r) * DIM_IN + c);
        wT[c + 0][r] = v.x; wT[c + 1][r] = v.y;
        wT[c + 2][r] = v.z; wT[c + 3][r] = v.w;
    }
    __syncthreads();

    const int k  = t & 63;                   // lane = k -> conflict-free wT reads
    const int nb = t >> 6;                   // wave-uniform -> xs reads broadcast
    const float bk = b[k0 + k];
    float z[4];
#pragma unroll
    for (int i = 0; i < 4; ++i) z[i] = bk;

    for (int d4 = 0; d4 < 64; d4 += 4) {
        float xv[4][4];
#pragma unroll
        for (int i = 0; i < 4; ++i)
            *(float4*)xv[i] = *(const float4*)&xs[nb * 4 + i][d4];
#pragma unroll
        for (int j = 0; j < 4; ++j) {
            const float wv = wT[d4 + j][k];
#pragma unroll
            for (int i = 0; i < 4; ++i) z[i] += xv[i][j] * wv;
        }
    }

    const float scale = 0.04419417382415922f;  // sqrt(2/1024)
    ushort4 ov;
    ov.x = f2bf(-scale * __sinf(z[0]));
    ov.y = f2bf(-scale * __sinf(z[1]));
    ov.z = f2bf(-scale * __sinf(z[2]));
    ov.w = f2bf(-scale * __sinf(z[3]));
    *(ushort4*)(sT + (size_t)(k0 + k) * N_OBS + n0 + nb * 4) = ov;
}

// ---------------------------------------------------------------------------
// Kernel 2 (FUSED gram + scale + expand):
// Per block (grid 16x16, 1 block/CU): compute the 64x64 M-tile
//   M[k,l] = (1/n) sum_n s[n,k] s[n,l]
// via a 3-buffer depth-2 global_load_lds pipeline with COUNTED vmcnt (T4):
// per iteration: vmcnt(4) [drains own stage(it), leaves stage(it+1) in
// flight] -> s_barrier [all waves' stage(it) landed] -> issue stage(it+2)
// [after barrier => readers of its target buffer (iter it-1) are done]
// -> ds_read + MFMA on buf[it%3]. Never drains to 0 except the tail.
// Then write all 64 d-planes:
//   out[d, k0+row, l0+col] = M[row,col] * w[k0+row,d] * w[l0+col,d]
// with full-line PLAIN f32x4 stores (A/B vs R3's nontemporal: every measured
// 6.3+ TB/s writer on this chip -- harness fills, m13 copy -- uses cached
// stores; nothing needs L2 protection since this is the kernel's last phase).
// LDS phases alias one 51 KB arena: phase-1 staging (3 x 16 KB) is dead
// before phase-2 writes M_lds/wkT/wlT (stride 68 floats).
// ---------------------------------------------------------------------------
__device__ __forceinline__ void stage_tiles(
    const ushort_t* __restrict__ sT, ushort_t* buf,
    int k0, int l0, int ncol0, int wv, int srow, int sslot) {
#pragma unroll
    for (int j = 0; j < 2; ++j) {
        const int c = wv * 2 + j;            // chunk 0..7, wave-uniform
        const ushort_t* gA = sT + (size_t)(k0 + c * 8 + srow) * N_OBS + ncol0 + sslot * 8;
        const ushort_t* gB = sT + (size_t)(l0 + c * 8 + srow) * N_OBS + ncol0 + sslot * 8;
        GLD_LDS16(gA, buf + c * 512);        // A: chunk c -> [c*1024B, +1024)
        GLD_LDS16(gB, buf + 4096 + c * 512); // B: second 8 KB half
    }
}

__global__ __launch_bounds__(256) void rff_gram_expand(
    const ushort_t* __restrict__ sT, const float* __restrict__ w,
    float* __restrict__ out) {
    __shared__ __align__(16) char smem[52224];
    ushort_t* stg   = (ushort_t*)smem;              // phase1: 3 bufs x 8192 bf16
    float*    M_lds = (float*)smem;                 // phase2+: [64][68]
    float*    wkT   = (float*)(smem + 17408);       // phase2+: [64][68] (d-major)
    float*    wlT   = (float*)(smem + 34816);       // phase2+: [64][68]

    const int t    = threadIdx.x;
    const int lane = t & 63;
    const int wv   = t >> 6;
    const int wr   = wv >> 1, wc = wv & 1;
    const int k0   = blockIdx.y * 64, l0 = blockIdx.x * 64;

    // Staging geometry: lds[row][slot] holds global col-slot (slot ^ (row&7)).
    const int srow  = lane >> 3;
    const int sslot = (lane & 7) ^ srow;

    f32x4 acc[2][2];
#pragma unroll
    for (int a = 0; a < 2; ++a)
#pragma unroll
        for (int bb = 0; bb < 2; ++bb)
            acc[a][bb] = (f32x4){0.f, 0.f, 0.f, 0.f};

    const int rlo = lane & 15;               // fragment row within 16
    const int hi  = lane >> 4;               // 0..3 -> k sub-slot
    const int rx  = rlo & 7;                 // row&7 for the read-side XOR

    // prologue: fill pipeline 2 deep (4 loads/wave each)
    stage_tiles(sT, stg,        k0, l0,  0, wv, srow, sslot);
    stage_tiles(sT, stg + 8192, k0, l0, 64, wv, srow, sslot);

    for (int it = 0; it < NCHUNK; ++it) {
        if (it == NCHUNK - 1) {              // tail: drain everything
            asm volatile("s_waitcnt vmcnt(0)" ::: "memory");
        } else {                             // steady: drain own stage(it) only
            asm volatile("s_waitcnt vmcnt(4)" ::: "memory");
        }
        __builtin_amdgcn_s_barrier();        // all waves' stage(it) landed
        if (it + 2 < NCHUNK)                 // issue stage(it+2); its buffer's
            stage_tiles(sT, stg + ((it + 2) % 3) * 8192,   // readers (it-1) are
                        k0, l0, (it + 2) * 64, wv, srow, sslot);  // past barrier
        const ushort_t* bufA = stg + (it % 3) * 8192;
        const ushort_t* bufB = bufA + 4096;
#pragma unroll
        for (int ks = 0; ks < 2; ++ks) {     // two K=32 steps per 64-chunk
            const int slot = (ks * 4 + hi) ^ rx;   // swizzled read slot
            bf16x8 af[2], bfr[2];
#pragma unroll
            for (int a = 0; a < 2; ++a) {
                af[a]  = *(const bf16x8*)(bufA + (wr * 32 + a * 16 + rlo) * 64 + slot * 8);
                bfr[a] = *(const bf16x8*)(bufB + (wc * 32 + a * 16 + rlo) * 64 + slot * 8);
            }
#pragma unroll
            for (int a = 0; a < 2; ++a)
#pragma unroll
                for (int bb = 0; bb < 2; ++bb)
                    acc[a][bb] = __builtin_amdgcn_mfma_f32_16x16x32_bf16(
                        af[a], bfr[bb], acc[a][bb], 0, 0, 0);
        }
    }
    __syncthreads();                         // all staging reads retired; LDS
                                             // arena may now be re-purposed

    // ---- phase 2: acc -> M_lds (scaled); w tiles -> LDS transposed ----
    const float inv_n = 1.0f / (float)N_OBS;
    const int col = lane & 15;
    const int rq  = (lane >> 4) * 4;
#pragma unroll
    for (int a = 0; a < 2; ++a)
#pragma unroll
        for (int bb = 0; bb < 2; ++bb)
#pragma unroll
            for (int r = 0; r < 4; ++r) {
                const int row = wr * 32 + a * 16 + rq + r;
                const int cl  = wc * 32 + bb * 16 + col;
                M_lds[row * 68 + cl] = acc[a][bb][r] * inv_n;
            }
#pragma unroll
    for (int i = 0; i < 4; ++i) {            // wkT[d][kk]=w[k0+kk][d], wlT likewise
        const int r = (t >> 4) + 16 * i, c = (t & 15) * 4;
        float4 vk = *(const float4*)(w + (k0 + r) * DIM_IN + c);
        float4 vl = *(const float4*)(w + (l0 + r) * DIM_IN + c);
        wkT[(c + 0) * 68 + r] = vk.x; wkT[(c + 1) * 68 + r] = vk.y;
        wkT[(c + 2) * 68 + r] = vk.z; wkT[(c + 3) * 68 + r] = vk.w;
        wlT[(c + 0) * 68 + r] = vl.x; wlT[(c + 1) * 68 + r] = vl.y;
        wlT[(c + 2) * 68 + r] = vl.z; wlT[(c + 3) * 68 + r] = vl.w;
    }
    __syncthreads();

    // ---- phase 3: d-sweep, 1 MB of plain full-line stores ----
    const int prow = t >> 4;                 // 0..15
    const int pcol = (t & 15) * 4;           // 0..60
    f32x4 mv[4];                             // M rows hoisted to registers
#pragma unroll
    for (int rr = 0; rr < 4; ++rr)
        mv[rr] = *(const f32x4*)&M_lds[(rr * 16 + prow) * 68 + pcol];

    float* outb = out + (size_t)k0 * K_HID + l0;
#pragma unroll 2
    for (int d = 0; d < DIM_IN; ++d) {
        const f32x4 wlv = *(const f32x4*)&wlT[d * 68 + pcol];
        float* outd = outb + (size_t)d * K_HID * K_HID;
#pragma unroll
        for (int rr = 0; rr < 4; ++rr) {
            const int row = rr * 16 + prow;
            const float wk = wkT[d * 68 + row];
            f32x4 o;
#pragma unroll
            for (int j = 0; j < 4; ++j) o[j] = mv[rr][j] * wk * wlv[j];
            *(f32x4*)(outd + (size_t)row * K_HID + pcol) = o;   // plain store (A/B vs NT)
        }
    }
}

// ---------------------------------------------------------------------------
extern "C" void kernel_launch(void* const* d_in, const int* in_sizes, int n_in,
                              void* d_out, int out_size, void* d_ws, size_t ws_size,
                              hipStream_t stream) {
    const float* x = (const float*)d_in[0];  // (2048, 64)
    const float* w = (const float*)d_in[1];  // (1024, 64)
    const float* b = (const float*)d_in[2];  // (1024,)
    float* out = (float*)d_out;              // (64, 1024, 1024)

    ushort_t* sT_buf = (ushort_t*)d_ws;      // 4 MB bf16 (1024 x 2048)

    rff_compute_s<<<dim3(K_HID / 64, N_OBS / 16), 256, 0, stream>>>(x, w, b, sT_buf);
    rff_gram_expand<<<dim3(K_HID / 64, K_HID / 64), 256, 0, stream>>>(sT_buf, w, out);
}